// Round 1
// baseline (2098.237 us; speedup 1.0000x reference)
//
#include <hip/hip_runtime.h>

// HashGridEncoder: x [N,3] f32 in [0,1), aabb [3] f32, table [16, 2^19, 2] f32
// out [N, 32] f32.  Levels 0..2 dense (res 16,32,64), levels 3..15 hashed.

#define TSZ  (1u << 19)
#define TMASK (TSZ - 1u)
#define PY   2654435761u
#define PZ   805459861u

__global__ __launch_bounds__(256) void hashgrid_enc_kernel(
    const float* __restrict__ x,
    const float* __restrict__ aabb,
    const float* __restrict__ tab,
    float* __restrict__ out,
    int n)
{
    int i = blockIdx.x * 256 + threadIdx.x;
    if (i >= n) return;

    const float ax = aabb[0], ay = aabb[1], az = aabb[2];
    // normalize: x/aabb -> (-1,1)->[0,1]
    const float xn = (x[3 * i + 0] / ax + 1.0f) * 0.5f;
    const float yn = (x[3 * i + 1] / ay + 1.0f) * 0.5f;
    const float zn = (x[3 * i + 2] / az + 1.0f) * 0.5f;

    float* orow = out + (size_t)i * 32;

    // ---- dense levels 0..2 (res 16, 32, 64) ----
    #pragma unroll
    for (int lvl = 0; lvl < 3; ++lvl) {
        const unsigned res = 16u << lvl;
        const float resf = (float)res;
        const float posx = xn * resf, posy = yn * resf, posz = zn * resf;
        const float fx = floorf(posx), fy = floorf(posy), fz = floorf(posz);
        const float tx = posx - fx, ty = posy - fy, tz = posz - fz;
        const unsigned cx = (unsigned)fx, cy = (unsigned)fy, cz = (unsigned)fz;
        const unsigned s = res + 1u;
        const unsigned s2 = s * s;
        const unsigned base = cx + cy * s + cz * s2;
        const float2* tl = (const float2*)tab + (size_t)lvl * TSZ;
        float2 e0 = tl[base];
        float2 e1 = tl[base + 1u];
        float2 e2 = tl[base + s];
        float2 e3 = tl[base + s + 1u];
        float2 e4 = tl[base + s2];
        float2 e5 = tl[base + s2 + 1u];
        float2 e6 = tl[base + s2 + s];
        float2 e7 = tl[base + s2 + s + 1u];
        const float wx1 = tx, wx0 = 1.0f - tx;
        const float wy1 = ty, wy0 = 1.0f - ty;
        const float wz1 = tz, wz0 = 1.0f - tz;
        const float wy0z0 = wy0 * wz0, wy1z0 = wy1 * wz0;
        const float wy0z1 = wy0 * wz1, wy1z1 = wy1 * wz1;
        const float w0 = wx0 * wy0z0, w1 = wx1 * wy0z0;
        const float w2 = wx0 * wy1z0, w3 = wx1 * wy1z0;
        const float w4 = wx0 * wy0z1, w5 = wx1 * wy0z1;
        const float w6 = wx0 * wy1z1, w7 = wx1 * wy1z1;
        float f0 = w0 * e0.x;
        float f1 = w0 * e0.y;
        f0 += w1 * e1.x;  f1 += w1 * e1.y;
        f0 += w2 * e2.x;  f1 += w2 * e2.y;
        f0 += w3 * e3.x;  f1 += w3 * e3.y;
        f0 += w4 * e4.x;  f1 += w4 * e4.y;
        f0 += w5 * e5.x;  f1 += w5 * e5.y;
        f0 += w6 * e6.x;  f1 += w6 * e6.y;
        f0 += w7 * e7.x;  f1 += w7 * e7.y;
        *(float2*)(orow + 2 * lvl) = make_float2(f0, f1);
    }

    // ---- hashed levels 3..15 ----
    for (int lvl = 3; lvl < 16; ++lvl) {
        const unsigned res = 16u << lvl;
        const float resf = (float)res;
        const float posx = xn * resf, posy = yn * resf, posz = zn * resf;
        const float fx = floorf(posx), fy = floorf(posy), fz = floorf(posz);
        const float tx = posx - fx, ty = posy - fy, tz = posz - fz;
        const unsigned cx = (unsigned)fx, cy = (unsigned)fy, cz = (unsigned)fz;
        const unsigned hx0 = cx,            hx1 = cx + 1u;
        const unsigned hy0 = cy * PY,       hy1 = hy0 + PY;   // (cy+1)*PY mod 2^32
        const unsigned hz0 = cz * PZ,       hz1 = hz0 + PZ;
        const unsigned i0 = (hx0 ^ hy0 ^ hz0) & TMASK;
        const unsigned i1 = (hx1 ^ hy0 ^ hz0) & TMASK;
        const unsigned i2 = (hx0 ^ hy1 ^ hz0) & TMASK;
        const unsigned i3 = (hx1 ^ hy1 ^ hz0) & TMASK;
        const unsigned i4 = (hx0 ^ hy0 ^ hz1) & TMASK;
        const unsigned i5 = (hx1 ^ hy0 ^ hz1) & TMASK;
        const unsigned i6 = (hx0 ^ hy1 ^ hz1) & TMASK;
        const unsigned i7 = (hx1 ^ hy1 ^ hz1) & TMASK;
        const float2* tl = (const float2*)tab + (size_t)lvl * TSZ;
        float2 e0 = tl[i0];
        float2 e1 = tl[i1];
        float2 e2 = tl[i2];
        float2 e3 = tl[i3];
        float2 e4 = tl[i4];
        float2 e5 = tl[i5];
        float2 e6 = tl[i6];
        float2 e7 = tl[i7];
        const float wx1 = tx, wx0 = 1.0f - tx;
        const float wy1 = ty, wy0 = 1.0f - ty;
        const float wz1 = tz, wz0 = 1.0f - tz;
        const float wy0z0 = wy0 * wz0, wy1z0 = wy1 * wz0;
        const float wy0z1 = wy0 * wz1, wy1z1 = wy1 * wz1;
        const float w0 = wx0 * wy0z0, w1 = wx1 * wy0z0;
        const float w2 = wx0 * wy1z0, w3 = wx1 * wy1z0;
        const float w4 = wx0 * wy0z1, w5 = wx1 * wy0z1;
        const float w6 = wx0 * wy1z1, w7 = wx1 * wy1z1;
        float f0 = w0 * e0.x;
        float f1 = w0 * e0.y;
        f0 += w1 * e1.x;  f1 += w1 * e1.y;
        f0 += w2 * e2.x;  f1 += w2 * e2.y;
        f0 += w3 * e3.x;  f1 += w3 * e3.y;
        f0 += w4 * e4.x;  f1 += w4 * e4.y;
        f0 += w5 * e5.x;  f1 += w5 * e5.y;
        f0 += w6 * e6.x;  f1 += w6 * e6.y;
        f0 += w7 * e7.x;  f1 += w7 * e7.y;
        *(float2*)(orow + 2 * lvl) = make_float2(f0, f1);
    }
}

extern "C" void kernel_launch(void* const* d_in, const int* in_sizes, int n_in,
                              void* d_out, int out_size, void* d_ws, size_t ws_size,
                              hipStream_t stream) {
    const float* x    = (const float*)d_in[0];
    const float* aabb = (const float*)d_in[1];
    const float* tab  = (const float*)d_in[2];
    float* out = (float*)d_out;
    const int n = in_sizes[0] / 3;
    const int blocks = (n + 255) / 256;
    hashgrid_enc_kernel<<<blocks, 256, 0, stream>>>(x, aabb, tab, out, n);
}

// Round 2
// 1101.812 us; speedup vs baseline: 1.9044x; 1.9044x over previous
//
#include <hip/hip_runtime.h>

// HashGridEncoder: x [N,3] f32, aabb [3] f32, table [16, 2^19, 2] f32
// out [N, 32] f32.  Levels 0..2 dense (res 16,32,64), levels 3..15 hashed.
//
// Strategy: level-phased dispatch (1-D grid, level-major order) so each
// XCD's 4MB L2 holds only the currently-active level's 4MB hash table.
// Writes go coalesced to ws[16][N] (float2), then an LDS transpose kernel
// emits the [N][32] output with full-line float4 stores.

#define TSZ   (1u << 19)
#define TMASK (TSZ - 1u)
#define PY    2654435761u
#define PZ    805459861u

template <int DIRECT>
__global__ __launch_bounds__(256) void enc_phased(
    const float* __restrict__ x,
    const float* __restrict__ aabb,
    const float* __restrict__ tab,
    float2* __restrict__ ws,      // [16][N] (DIRECT=0)
    float* __restrict__ out,      // [N][32] (DIRECT=1)
    int n, int chunks_per_level)
{
    const int lin   = blockIdx.x;
    const int lvl   = lin / chunks_per_level;
    const int chunk = lin - lvl * chunks_per_level;
    const int i     = chunk * 256 + threadIdx.x;
    if (i >= n) return;

    const float ax = aabb[0], ay = aabb[1], az = aabb[2];
    const float xn = (x[3 * i + 0] / ax + 1.0f) * 0.5f;
    const float yn = (x[3 * i + 1] / ay + 1.0f) * 0.5f;
    const float zn = (x[3 * i + 2] / az + 1.0f) * 0.5f;

    const unsigned res = 16u << lvl;
    const float resf = (float)res;
    const float posx = xn * resf, posy = yn * resf, posz = zn * resf;
    const float fx = floorf(posx), fy = floorf(posy), fz = floorf(posz);
    const float tx = posx - fx, ty = posy - fy, tz = posz - fz;
    const unsigned cx = (unsigned)fx, cy = (unsigned)fy, cz = (unsigned)fz;

    unsigned i0, i1, i2, i3, i4, i5, i6, i7;
    if (lvl < 3) {
        // dense level: row-major (res+1)^3 indexing
        const unsigned s  = res + 1u;
        const unsigned s2 = s * s;
        const unsigned base = cx + cy * s + cz * s2;
        i0 = base;           i1 = base + 1u;
        i2 = base + s;       i3 = base + s + 1u;
        i4 = base + s2;      i5 = base + s2 + 1u;
        i6 = base + s2 + s;  i7 = base + s2 + s + 1u;
    } else {
        const unsigned hx0 = cx,        hx1 = cx + 1u;
        const unsigned hy0 = cy * PY,   hy1 = hy0 + PY;
        const unsigned hz0 = cz * PZ,   hz1 = hz0 + PZ;
        i0 = (hx0 ^ hy0 ^ hz0) & TMASK;
        i1 = (hx1 ^ hy0 ^ hz0) & TMASK;
        i2 = (hx0 ^ hy1 ^ hz0) & TMASK;
        i3 = (hx1 ^ hy1 ^ hz0) & TMASK;
        i4 = (hx0 ^ hy0 ^ hz1) & TMASK;
        i5 = (hx1 ^ hy0 ^ hz1) & TMASK;
        i6 = (hx0 ^ hy1 ^ hz1) & TMASK;
        i7 = (hx1 ^ hy1 ^ hz1) & TMASK;
    }

    const float2* tl = (const float2*)tab + (size_t)lvl * TSZ;
    const float2 e0 = tl[i0];
    const float2 e1 = tl[i1];
    const float2 e2 = tl[i2];
    const float2 e3 = tl[i3];
    const float2 e4 = tl[i4];
    const float2 e5 = tl[i5];
    const float2 e6 = tl[i6];
    const float2 e7 = tl[i7];

    const float wx1 = tx, wx0 = 1.0f - tx;
    const float wy1 = ty, wy0 = 1.0f - ty;
    const float wz1 = tz, wz0 = 1.0f - tz;
    const float wy0z0 = wy0 * wz0, wy1z0 = wy1 * wz0;
    const float wy0z1 = wy0 * wz1, wy1z1 = wy1 * wz1;
    const float w0 = wx0 * wy0z0, w1 = wx1 * wy0z0;
    const float w2 = wx0 * wy1z0, w3 = wx1 * wy1z0;
    const float w4 = wx0 * wy0z1, w5 = wx1 * wy0z1;
    const float w6 = wx0 * wy1z1, w7 = wx1 * wy1z1;

    float f0 = w0 * e0.x, f1 = w0 * e0.y;
    f0 += w1 * e1.x;  f1 += w1 * e1.y;
    f0 += w2 * e2.x;  f1 += w2 * e2.y;
    f0 += w3 * e3.x;  f1 += w3 * e3.y;
    f0 += w4 * e4.x;  f1 += w4 * e4.y;
    f0 += w5 * e5.x;  f1 += w5 * e5.y;
    f0 += w6 * e6.x;  f1 += w6 * e6.y;
    f0 += w7 * e7.x;  f1 += w7 * e7.y;

    if (DIRECT) {
        *(float2*)(out + (size_t)i * 32 + 2 * lvl) = make_float2(f0, f1);
    } else {
        ws[(size_t)lvl * n + i] = make_float2(f0, f1);
    }
}

// Transpose ws[16][N] float2 -> out[N][32] float with full-line float4 stores.
__global__ __launch_bounds__(256) void transpose_out(
    const float2* __restrict__ ws,
    float* __restrict__ out,
    int n)
{
    __shared__ float2 t[16][256];
    const int base = blockIdx.x * 256;
    const int tid  = threadIdx.x;
    const int i    = base + tid;

    if (i < n) {
        #pragma unroll
        for (int lvl = 0; lvl < 16; ++lvl) {
            t[lvl][tid] = ws[(size_t)lvl * n + i];
        }
    }
    __syncthreads();

    if (i < n) {
        float* orow = out + (size_t)i * 32;
        #pragma unroll
        for (int k = 0; k < 8; ++k) {
            const float2 a = t[2 * k][tid];
            const float2 b = t[2 * k + 1][tid];
            *(float4*)(orow + 4 * k) = make_float4(a.x, a.y, b.x, b.y);
        }
    }
}

extern "C" void kernel_launch(void* const* d_in, const int* in_sizes, int n_in,
                              void* d_out, int out_size, void* d_ws, size_t ws_size,
                              hipStream_t stream) {
    const float* x    = (const float*)d_in[0];
    const float* aabb = (const float*)d_in[1];
    const float* tab  = (const float*)d_in[2];
    float* out = (float*)d_out;
    const int n = in_sizes[0] / 3;

    const int chunks = (n + 255) / 256;
    const int grid   = 16 * chunks;
    const size_t ws_needed = (size_t)16 * n * sizeof(float2);

    if (ws_size >= ws_needed) {
        float2* ws = (float2*)d_ws;
        enc_phased<0><<<grid, 256, 0, stream>>>(x, aabb, tab, ws, out, n, chunks);
        transpose_out<<<chunks, 256, 0, stream>>>(ws, out, n);
    } else {
        enc_phased<1><<<grid, 256, 0, stream>>>(x, aabb, tab, nullptr, out, n, chunks);
    }
}